// Round 1
// baseline (530.191 us; speedup 1.0000x reference)
//
#include <hip/hip_runtime.h>
#include <cstdint>
#include <cstddef>

// Problem dims (fixed by the reference)
#define MDIM 16384    // B_SZ * L
#define HDIM 1024
#define PDIM 1024
#define LSEQ 4096
#define BSZ  4
#define CHUNK 64
#define NCHUNK 64     // LSEQ / CHUNK

typedef float   floatx4  __attribute__((ext_vector_type(4)));
typedef __bf16  bf16x8   __attribute__((ext_vector_type(8)));
typedef unsigned short ushortx8 __attribute__((ext_vector_type(8)));
typedef unsigned short ushortx4 __attribute__((ext_vector_type(4)));

// fp32 -> bf16 round-to-nearest-even
__device__ __forceinline__ unsigned short f2bf(float f) {
    union { float f; uint32_t u; } v; v.f = f;
    return (unsigned short)((v.u + 0x7fffu + ((v.u >> 16) & 1u)) >> 16);
}

__device__ __forceinline__ bf16x8 ldfrag(const unsigned short* p) {
    return __builtin_bit_cast(bf16x8, *(const ushortx8*)p);
}

// LDS row stride (bf16 elems): 32 data + 8 pad = 80B rows, 16B-aligned, 2-way banks (free)
#define LDT 40

// ---------------------------------------------------------------------------
// Kernel 1: Bu = (B_re + i B_im) * gamma  @  u^T    (two GEMMs sharing A-tile)
//   U   [MDIM, HDIM] fp32, Bre/Bim [PDIM, HDIM] fp32 (B^T layout for GEMM)
//   BuC [MDIM, PDIM, 2] fp32 interleaved (re, im), gamma applied in epilogue
// Block: 256 thr = 4 waves, tile 128(M) x 64(N), BK=32, wave tile 64x32.
// ---------------------------------------------------------------------------
__global__ __launch_bounds__(256) void gemm_bu_kernel(
    const float* __restrict__ U,
    const float* __restrict__ Bre,
    const float* __restrict__ Bim,
    const float* __restrict__ gamma_log,
    float* __restrict__ BuC)
{
    __shared__ unsigned short sA[128 * LDT];
    __shared__ unsigned short sBr[64 * LDT];
    __shared__ unsigned short sBi[64 * LDT];

    const int tid  = threadIdx.x;
    const int wave = tid >> 6, lane = tid & 63;
    const int m0 = blockIdx.x * 128;
    const int n0 = blockIdx.y * 64;
    const int wm = (wave >> 1) * 64, wn = (wave & 1) * 32;
    const int lrow = lane & 15, lq = lane >> 4;

    floatx4 accR[4][2] = {};
    floatx4 accI[4][2] = {};

    for (int k0 = 0; k0 < HDIM; k0 += 32) {
        // stage A: 128x32 (1024 float4 chunks / 256 threads)
        #pragma unroll
        for (int s = 0; s < 4; ++s) {
            int c = tid + s * 256;
            int row = c >> 3, kk = (c & 7) * 4;
            const float4 v = *(const float4*)(U + (size_t)(m0 + row) * HDIM + k0 + kk);
            ushortx4 w; w[0]=f2bf(v.x); w[1]=f2bf(v.y); w[2]=f2bf(v.z); w[3]=f2bf(v.w);
            *(ushortx4*)(sA + row * LDT + kk) = w;
        }
        // stage Bre/Bim: 64x32 each (512 chunks / 256 threads)
        #pragma unroll
        for (int s = 0; s < 2; ++s) {
            int c = tid + s * 256;
            int row = c >> 3, kk = (c & 7) * 4;
            const float4 vr = *(const float4*)(Bre + (size_t)(n0 + row) * HDIM + k0 + kk);
            ushortx4 wr; wr[0]=f2bf(vr.x); wr[1]=f2bf(vr.y); wr[2]=f2bf(vr.z); wr[3]=f2bf(vr.w);
            *(ushortx4*)(sBr + row * LDT + kk) = wr;
            const float4 vi = *(const float4*)(Bim + (size_t)(n0 + row) * HDIM + k0 + kk);
            ushortx4 wi; wi[0]=f2bf(vi.x); wi[1]=f2bf(vi.y); wi[2]=f2bf(vi.z); wi[3]=f2bf(vi.w);
            *(ushortx4*)(sBi + row * LDT + kk) = wi;
        }
        __syncthreads();

        bf16x8 af[4], br[2], bi[2];
        #pragma unroll
        for (int mt = 0; mt < 4; ++mt)
            af[mt] = ldfrag(sA + (wm + mt * 16 + lrow) * LDT + lq * 8);
        #pragma unroll
        for (int nt = 0; nt < 2; ++nt) {
            br[nt] = ldfrag(sBr + (wn + nt * 16 + lrow) * LDT + lq * 8);
            bi[nt] = ldfrag(sBi + (wn + nt * 16 + lrow) * LDT + lq * 8);
        }
        #pragma unroll
        for (int mt = 0; mt < 4; ++mt)
            #pragma unroll
            for (int nt = 0; nt < 2; ++nt) {
                accR[mt][nt] = __builtin_amdgcn_mfma_f32_16x16x32_bf16(af[mt], br[nt], accR[mt][nt], 0, 0, 0);
                accI[mt][nt] = __builtin_amdgcn_mfma_f32_16x16x32_bf16(af[mt], bi[nt], accI[mt][nt], 0, 0, 0);
            }
        __syncthreads();
    }

    const int r0 = lq * 4;
    #pragma unroll
    for (int nt = 0; nt < 2; ++nt) {
        int col = n0 + wn + nt * 16 + lrow;
        float g = expf(gamma_log[col]);
        #pragma unroll
        for (int mt = 0; mt < 4; ++mt)
            #pragma unroll
            for (int r = 0; r < 4; ++r) {
                int row = m0 + wm + mt * 16 + r0 + r;
                float2 v; v.x = accR[mt][nt][r] * g; v.y = accI[mt][nt][r] * g;
                *(float2*)(BuC + ((size_t)row * PDIM + col) * 2) = v;
            }
    }
}

// ---------------------------------------------------------------------------
// Scan pass A: per-chunk local end states (start from 0). Thread = (b,c,p).
// ---------------------------------------------------------------------------
__global__ __launch_bounds__(256) void scan_passA(
    const float* __restrict__ BuC,
    const float* __restrict__ nu_log, const float* __restrict__ theta_log,
    float* __restrict__ endC)
{
    int tid = blockIdx.x * 256 + threadIdx.x;           // 0 .. 262143
    int p = tid & (PDIM - 1);
    int c = (tid >> 10) & (NCHUNK - 1);
    int b = tid >> 16;
    float nu = expf(nu_log[p]);
    float th = expf(theta_log[p]);
    float el = expf(-nu);
    float lr = el * cosf(th), li = el * sinf(th);
    const float* src = BuC + ((size_t)(b * LSEQ + c * CHUNK) * PDIM + p) * 2;
    float xr = 0.f, xi = 0.f;
    #pragma unroll 8
    for (int t = 0; t < CHUNK; ++t) {
        float2 bu = *(const float2*)(src + (size_t)t * (PDIM * 2));
        float nr = fmaf(lr, xr, fmaf(-li, xi, bu.x));
        float ni = fmaf(lr, xi, fmaf(li, xr, bu.y));
        xr = nr; xi = ni;
    }
    float2 e; e.x = xr; e.y = xi;
    *(float2*)(endC + (size_t)tid * 2) = e;
}

// ---------------------------------------------------------------------------
// Scan pass B: carry prefix across chunks. Thread = (b,p); 64 sequential steps.
// carryC[b][c][p] = global state ENTERING chunk c.  lambda^CHUNK closed-form.
// ---------------------------------------------------------------------------
__global__ __launch_bounds__(256) void scan_passB(
    const float* __restrict__ endC,
    const float* __restrict__ nu_log, const float* __restrict__ theta_log,
    float* __restrict__ carryC)
{
    int tid = blockIdx.x * 256 + threadIdx.x;           // 0 .. 4095
    int p = tid & (PDIM - 1);
    int b = tid >> 10;
    float nu = expf(nu_log[p]);
    float th = expf(theta_log[p]);
    float e64 = expf(-nu * (float)CHUNK);
    float a = th * (float)CHUNK;
    float Lr = e64 * cosf(a), Li = e64 * sinf(a);
    float gr = 0.f, gi = 0.f;
    for (int c = 0; c < NCHUNK; ++c) {
        size_t idx = (((size_t)b * NCHUNK + c) * PDIM + p) * 2;
        float2 g; g.x = gr; g.y = gi;
        *(float2*)(carryC + idx) = g;
        float2 e = *(const float2*)(endC + idx);
        float nr = fmaf(Lr, gr, fmaf(-Li, gi, e.x));
        float ni = fmaf(Lr, gi, fmaf(Li, gr, e.y));
        gr = nr; gi = ni;
    }
}

// ---------------------------------------------------------------------------
// Scan pass C: re-scan each chunk from its true entering state; write x
// in place over BuC. Thread = (b,c,p).
// ---------------------------------------------------------------------------
__global__ __launch_bounds__(256) void scan_passC(
    float* __restrict__ BuC,
    const float* __restrict__ nu_log, const float* __restrict__ theta_log,
    const float* __restrict__ carryC)
{
    int tid = blockIdx.x * 256 + threadIdx.x;           // 0 .. 262143
    int p = tid & (PDIM - 1);
    int c = (tid >> 10) & (NCHUNK - 1);
    int b = tid >> 16;
    float nu = expf(nu_log[p]);
    float th = expf(theta_log[p]);
    float el = expf(-nu);
    float lr = el * cosf(th), li = el * sinf(th);
    float2 g = *(const float2*)(carryC + (size_t)tid * 2);
    float xr = g.x, xi = g.y;
    float* ptr = BuC + ((size_t)(b * LSEQ + c * CHUNK) * PDIM + p) * 2;
    #pragma unroll 8
    for (int t = 0; t < CHUNK; ++t) {
        float* q = ptr + (size_t)t * (PDIM * 2);
        float2 bu = *(const float2*)q;
        float nr = fmaf(lr, xr, fmaf(-li, xi, bu.x));
        float ni = fmaf(lr, xi, fmaf(li, xr, bu.y));
        xr = nr; xi = ni;
        float2 o; o.x = xr; o.y = xi;
        *(float2*)q = o;
    }
}

// ---------------------------------------------------------------------------
// Prep: Bc[h][2k]   = C_re[h][k]
//       Bc[h][2k+1] = -C_im[h][k]      (so gemm_out is a plain K=2048 GEMM)
// ---------------------------------------------------------------------------
__global__ __launch_bounds__(256) void prep_bc(
    const float* __restrict__ Cre, const float* __restrict__ Cim,
    float* __restrict__ Bc)
{
    int tid = blockIdx.x * 256 + threadIdx.x;           // 0 .. 1048575
    float2 v; v.x = Cre[tid]; v.y = -Cim[tid];
    *(float2*)(Bc + (size_t)tid * 2) = v;
}

// ---------------------------------------------------------------------------
// Kernel 3: out = Re(C x) + D .* u  as one GEMM with interleaved K=2048.
//   XC [MDIM, 2*PDIM] interleaved x, Bc [HDIM, 2*PDIM] interleaved (Cre,-Cim)
// Block: 256 thr = 4 waves, tile 128x128, BK=32, wave tile 64x64.
// ---------------------------------------------------------------------------
__global__ __launch_bounds__(256) void gemm_out_kernel(
    const float* __restrict__ XC,
    const float* __restrict__ Bc,
    const float* __restrict__ Dv,
    const float* __restrict__ U,
    float* __restrict__ out)
{
    __shared__ unsigned short sA[128 * LDT];
    __shared__ unsigned short sB[128 * LDT];

    const int tid  = threadIdx.x;
    const int wave = tid >> 6, lane = tid & 63;
    const int m0 = blockIdx.x * 128;
    const int n0 = blockIdx.y * 128;
    const int wm = (wave >> 1) * 64, wn = (wave & 1) * 64;
    const int lrow = lane & 15, lq = lane >> 4;

    floatx4 acc[4][4] = {};

    for (int k0 = 0; k0 < 2 * PDIM; k0 += 32) {
        #pragma unroll
        for (int s = 0; s < 4; ++s) {
            int c = tid + s * 256;
            int row = c >> 3, kk = (c & 7) * 4;
            const float4 va = *(const float4*)(XC + (size_t)(m0 + row) * (2 * PDIM) + k0 + kk);
            ushortx4 wa; wa[0]=f2bf(va.x); wa[1]=f2bf(va.y); wa[2]=f2bf(va.z); wa[3]=f2bf(va.w);
            *(ushortx4*)(sA + row * LDT + kk) = wa;
            const float4 vb = *(const float4*)(Bc + (size_t)(n0 + row) * (2 * PDIM) + k0 + kk);
            ushortx4 wb; wb[0]=f2bf(vb.x); wb[1]=f2bf(vb.y); wb[2]=f2bf(vb.z); wb[3]=f2bf(vb.w);
            *(ushortx4*)(sB + row * LDT + kk) = wb;
        }
        __syncthreads();

        bf16x8 af[4], bf[4];
        #pragma unroll
        for (int mt = 0; mt < 4; ++mt)
            af[mt] = ldfrag(sA + (wm + mt * 16 + lrow) * LDT + lq * 8);
        #pragma unroll
        for (int nt = 0; nt < 4; ++nt)
            bf[nt] = ldfrag(sB + (wn + nt * 16 + lrow) * LDT + lq * 8);
        #pragma unroll
        for (int mt = 0; mt < 4; ++mt)
            #pragma unroll
            for (int nt = 0; nt < 4; ++nt)
                acc[mt][nt] = __builtin_amdgcn_mfma_f32_16x16x32_bf16(af[mt], bf[nt], acc[mt][nt], 0, 0, 0);
        __syncthreads();
    }

    const int r0 = lq * 4;
    #pragma unroll
    for (int nt = 0; nt < 4; ++nt) {
        int col = n0 + wn + nt * 16 + lrow;
        float d = Dv[col];
        #pragma unroll
        for (int mt = 0; mt < 4; ++mt)
            #pragma unroll
            for (int r = 0; r < 4; ++r) {
                int row = m0 + wm + mt * 16 + r0 + r;
                size_t o = (size_t)row * HDIM + col;
                out[o] = acc[mt][nt][r] + d * U[o];
            }
    }
}

// ---------------------------------------------------------------------------
extern "C" void kernel_launch(void* const* d_in, const int* in_sizes, int n_in,
                              void* d_out, int out_size, void* d_ws, size_t ws_size,
                              hipStream_t stream)
{
    (void)in_sizes; (void)n_in; (void)out_size; (void)ws_size;
    const float* U         = (const float*)d_in[0];
    const float* nu_log    = (const float*)d_in[1];
    const float* theta_log = (const float*)d_in[2];
    const float* B_re      = (const float*)d_in[3];
    const float* B_im      = (const float*)d_in[4];
    const float* C_re      = (const float*)d_in[5];
    const float* C_im      = (const float*)d_in[6];
    const float* Dv        = (const float*)d_in[7];
    const float* gamma_log = (const float*)d_in[8];
    float* out = (float*)d_out;

    float* ws     = (float*)d_ws;
    float* BuC    = ws;                                  // MDIM*PDIM*2 = 33554432 f
    float* endC   = BuC  + (size_t)MDIM * PDIM * 2;      // 524288 f
    float* carryC = endC + (size_t)BSZ * NCHUNK * PDIM * 2;  // 524288 f
    float* Bc     = carryC + (size_t)BSZ * NCHUNK * PDIM * 2; // 2097152 f
    // total ws: ~140 MB

    prep_bc<<<(HDIM * PDIM) / 256, 256, 0, stream>>>(C_re, C_im, Bc);

    dim3 g1(MDIM / 128, PDIM / 64);
    gemm_bu_kernel<<<g1, 256, 0, stream>>>(U, B_re, B_im, gamma_log, BuC);

    const int nscan = BSZ * NCHUNK * PDIM;               // 262144
    scan_passA<<<nscan / 256, 256, 0, stream>>>(BuC, nu_log, theta_log, endC);
    scan_passB<<<(BSZ * PDIM) / 256, 256, 0, stream>>>(endC, nu_log, theta_log, carryC);
    scan_passC<<<nscan / 256, 256, 0, stream>>>(BuC, nu_log, theta_log, carryC);

    dim3 g3(MDIM / 128, HDIM / 128);
    gemm_out_kernel<<<g3, 256, 0, stream>>>(BuC, Bc, Dv, U, out);
}

// Round 2
// 359.458 us; speedup vs baseline: 1.4750x; 1.4750x over previous
//
#include <hip/hip_runtime.h>
#include <cstdint>
#include <cstddef>

// Problem dims (fixed by the reference)
#define MDIM 16384    // B_SZ * L
#define HDIM 1024
#define PDIM 1024
#define LSEQ 4096
#define BSZ  4
#define CHUNK 64
#define NCHUNK 64     // LSEQ / CHUNK
#define NBU  2048     // 2*PDIM (interleaved re/im)

typedef float   floatx4  __attribute__((ext_vector_type(4)));
typedef __bf16  bf16x8   __attribute__((ext_vector_type(8)));
typedef unsigned short u16;
typedef unsigned short u16x8 __attribute__((ext_vector_type(8)));
typedef unsigned short u16x4 __attribute__((ext_vector_type(4)));

// fp32 -> bf16 round-to-nearest-even
__device__ __forceinline__ u16 f2bf(float f) {
    union { float f; uint32_t u; } v; v.f = f;
    return (u16)((v.u + 0x7fffu + ((v.u >> 16) & 1u)) >> 16);
}
__device__ __forceinline__ float bfu2f(uint32_t bits16) {
    union { float f; uint32_t u; } v; v.u = bits16 << 16; return v.f;
}
__device__ __forceinline__ bf16x8 ldfrag(const u16* p) {
    return __builtin_bit_cast(bf16x8, *(const u16x8*)p);
}
// async global->LDS, 16B per lane; LDS deposit = uniform base + lane*16
__device__ __forceinline__ void gload16(const u16* g, u16* l) {
    __builtin_amdgcn_global_load_lds(
        (const __attribute__((address_space(1))) uint32_t*)g,
        (__attribute__((address_space(3))) uint32_t*)l, 16, 0, 0);
}

// ---------------------------------------------------------------------------
// Unified bf16 MFMA GEMM core: C[128x128] tile, BK=64, global_load_lds
// staging, XOR-swizzled LDS (swizzle applied on the SOURCE address since the
// LDS deposit is fixed lane*16). A [M x KD], B [N x KD] row-major bf16.
// LDS row = 64 bf16 = 128 B, physical chunk pc (16B) of row r holds logical
// chunk pc ^ (r&7)  -> fragment ds_read_b128 spreads across all 32 banks.
// ---------------------------------------------------------------------------
template<int KD>
__device__ __forceinline__ void gemm_core(
    const u16* __restrict__ A, const u16* __restrict__ B,
    int m0, int n0, u16* sA, u16* sB, floatx4 acc[4][4])
{
    const int tid  = threadIdx.x;
    const int wave = tid >> 6, lane = tid & 63;
    const int lrow = lane & 15, lq = lane >> 4;
    const int wm = (wave >> 1) * 64, wn = (wave & 1) * 64;
    const int srow   = lane >> 3;            // 0..7 row within 8-row group
    const int schunk = (lane & 7) ^ srow;    // swizzled logical 16B chunk

    const u16* aptr = A + (size_t)(m0 + wave * 32 + srow) * KD + schunk * 8;
    const u16* bptr = B + (size_t)(n0 + wave * 32 + srow) * KD + schunk * 8;
    u16* sAw = sA + wave * 32 * 64;
    u16* sBw = sB + wave * 32 * 64;

    for (int k0 = 0; k0 < KD; k0 += 64) {
        #pragma unroll
        for (int i = 0; i < 4; ++i) {
            gload16(aptr + (size_t)i * 8 * KD + k0, sAw + i * 8 * 64);
            gload16(bptr + (size_t)i * 8 * KD + k0, sBw + i * 8 * 64);
        }
        __syncthreads();   // drains vmcnt before barrier
        #pragma unroll
        for (int s = 0; s < 2; ++s) {
            bf16x8 af[4], bfr[4];
            #pragma unroll
            for (int mt = 0; mt < 4; ++mt) {
                int r = wm + mt * 16 + lrow;
                af[mt] = ldfrag(sA + r * 64 + (((s * 4 + lq) ^ (r & 7)) * 8));
            }
            #pragma unroll
            for (int nt = 0; nt < 4; ++nt) {
                int r = wn + nt * 16 + lrow;
                bfr[nt] = ldfrag(sB + r * 64 + (((s * 4 + lq) ^ (r & 7)) * 8));
            }
            #pragma unroll
            for (int mt = 0; mt < 4; ++mt)
                #pragma unroll
                for (int nt = 0; nt < 4; ++nt)
                    acc[mt][nt] = __builtin_amdgcn_mfma_f32_16x16x32_bf16(
                        af[mt], bfr[nt], acc[mt][nt], 0, 0, 0);
        }
        __syncthreads();
    }
}

// ---------------------------------------------------------------------------
// Kernel: Bu = Ubf @ Bcomb^T  (M=16384, N=2048, K=1024), output bf16
// Bcomb rows: n=2p   -> gamma[p]*B_re[p,:],  n=2p+1 -> gamma[p]*B_im[p,:]
// so output row m is already the interleaved (re,im) Bu layout.
// ---------------------------------------------------------------------------
__global__ __launch_bounds__(256) void gemm_bu_k(
    const u16* __restrict__ A, const u16* __restrict__ B, u16* __restrict__ O)
{
    __shared__ u16 sA[128 * 64];
    __shared__ u16 sB[128 * 64];
    floatx4 acc[4][4] = {};
    const int m0 = blockIdx.x * 128, n0 = blockIdx.y * 128;
    gemm_core<HDIM>(A, B, m0, n0, sA, sB, acc);

    const int tid = threadIdx.x, wave = tid >> 6, lane = tid & 63;
    const int lrow = lane & 15, lq = lane >> 4;
    const int wm = (wave >> 1) * 64, wn = (wave & 1) * 64;
    #pragma unroll
    for (int nt = 0; nt < 4; ++nt) {
        int col = n0 + wn + nt * 16 + lrow;
        #pragma unroll
        for (int mt = 0; mt < 4; ++mt)
            #pragma unroll
            for (int r = 0; r < 4; ++r) {
                int row = m0 + wm + mt * 16 + lq * 4 + r;
                O[(size_t)row * NBU + col] = f2bf(acc[mt][nt][r]);
            }
    }
}

// ---------------------------------------------------------------------------
// Kernel: out = Re(C x) + D.*u  (M=16384, N=1024, K=2048), output fp32
// A = x interleaved bf16 [M x 2048]; B = Bcbf [1024 x 2048] = (Cre,-Cim).
// ---------------------------------------------------------------------------
__global__ __launch_bounds__(256) void gemm_out_k(
    const u16* __restrict__ A, const u16* __restrict__ B,
    const float* __restrict__ Dv, const u16* __restrict__ Ubf,
    float* __restrict__ O)
{
    __shared__ u16 sA[128 * 64];
    __shared__ u16 sB[128 * 64];
    floatx4 acc[4][4] = {};
    const int m0 = blockIdx.x * 128, n0 = blockIdx.y * 128;
    gemm_core<NBU>(A, B, m0, n0, sA, sB, acc);

    const int tid = threadIdx.x, wave = tid >> 6, lane = tid & 63;
    const int lrow = lane & 15, lq = lane >> 4;
    const int wm = (wave >> 1) * 64, wn = (wave & 1) * 64;
    #pragma unroll
    for (int nt = 0; nt < 4; ++nt) {
        int col = n0 + wn + nt * 16 + lrow;
        float d = Dv[col];
        #pragma unroll
        for (int mt = 0; mt < 4; ++mt)
            #pragma unroll
            for (int r = 0; r < 4; ++r) {
                int row = m0 + wm + mt * 16 + lq * 4 + r;
                size_t o = (size_t)row * HDIM + col;
                O[o] = acc[mt][nt][r] + d * bfu2f(Ubf[o]);
            }
    }
}

// ---------------------------------------------------------------------------
// Prep kernels: one-time fp32 -> bf16 conversions
// ---------------------------------------------------------------------------
__global__ __launch_bounds__(256) void cvt_u_bf(
    const float* __restrict__ in, u16* __restrict__ out)
{
    size_t i = ((size_t)blockIdx.x * 256 + threadIdx.x) * 8;
    float4 a = *(const float4*)(in + i);
    float4 b = *(const float4*)(in + i + 4);
    u16x8 w;
    w[0]=f2bf(a.x); w[1]=f2bf(a.y); w[2]=f2bf(a.z); w[3]=f2bf(a.w);
    w[4]=f2bf(b.x); w[5]=f2bf(b.y); w[6]=f2bf(b.z); w[7]=f2bf(b.w);
    *(u16x8*)(out + i) = w;
}

// Bcomb[n=2p+s][h] = bf16(gamma[p] * (s? B_im : B_re)[p][h])
__global__ __launch_bounds__(256) void prep_bcomb(
    const float* __restrict__ Bre, const float* __restrict__ Bim,
    const float* __restrict__ gamma_log, u16* __restrict__ out)
{
    int t = blockIdx.x * 256 + threadIdx.x;        // 2048*1024/8 = 262144
    int n = t >> 7;
    int h = (t & 127) * 8;
    int p = n >> 1, s = n & 1;
    const float* src = (s ? Bim : Bre) + (size_t)p * HDIM + h;
    float g = expf(gamma_log[p]);
    float4 a = *(const float4*)src;
    float4 b = *(const float4*)(src + 4);
    u16x8 w;
    w[0]=f2bf(a.x*g); w[1]=f2bf(a.y*g); w[2]=f2bf(a.z*g); w[3]=f2bf(a.w*g);
    w[4]=f2bf(b.x*g); w[5]=f2bf(b.y*g); w[6]=f2bf(b.z*g); w[7]=f2bf(b.w*g);
    *(u16x8*)(out + (size_t)n * HDIM + h) = w;
}

// Bcbf[h][2k]=bf16(Cre[h][k]); Bcbf[h][2k+1]=bf16(-Cim[h][k])
__global__ __launch_bounds__(256) void prep_bc(
    const float* __restrict__ Cre, const float* __restrict__ Cim,
    u16* __restrict__ out)
{
    int t = blockIdx.x * 256 + threadIdx.x;        // 1024*1024/4 = 262144
    int h = t >> 8;
    int k = (t & 255) * 4;
    float4 cr = *(const float4*)(Cre + (size_t)h * PDIM + k);
    float4 ci = *(const float4*)(Cim + (size_t)h * PDIM + k);
    u16x8 w;
    w[0]=f2bf(cr.x); w[1]=f2bf(-ci.x);
    w[2]=f2bf(cr.y); w[3]=f2bf(-ci.y);
    w[4]=f2bf(cr.z); w[5]=f2bf(-ci.z);
    w[6]=f2bf(cr.w); w[7]=f2bf(-ci.w);
    *(u16x8*)(out + (size_t)h * NBU + 2 * k) = w;
}

// ---------------------------------------------------------------------------
// Scan pass A: per-chunk local end states (bf16 Bu in, fp32 state out)
// ---------------------------------------------------------------------------
__global__ __launch_bounds__(256) void scan_passA(
    const uint32_t* __restrict__ BuC,
    const float* __restrict__ nu_log, const float* __restrict__ theta_log,
    float* __restrict__ endC)
{
    int tid = blockIdx.x * 256 + threadIdx.x;           // 0 .. 262143
    int p = tid & (PDIM - 1);
    int c = (tid >> 10) & (NCHUNK - 1);
    int b = tid >> 16;
    float nu = expf(nu_log[p]);
    float th = expf(theta_log[p]);
    float el = expf(-nu);
    float lr = el * cosf(th), li = el * sinf(th);
    const uint32_t* src = BuC + (size_t)(b * LSEQ + c * CHUNK) * PDIM + p;
    float xr = 0.f, xi = 0.f;
    #pragma unroll 8
    for (int t = 0; t < CHUNK; ++t) {
        uint32_t v = src[(size_t)t * PDIM];
        float br = bfu2f(v & 0xffffu), bi = bfu2f(v >> 16);
        float nr = fmaf(lr, xr, fmaf(-li, xi, br));
        float ni = fmaf(lr, xi, fmaf(li, xr, bi));
        xr = nr; xi = ni;
    }
    float2 e; e.x = xr; e.y = xi;
    *(float2*)(endC + (size_t)tid * 2) = e;
}

// ---------------------------------------------------------------------------
// Scan pass B: carry prefix across chunks (fp32)
// ---------------------------------------------------------------------------
__global__ __launch_bounds__(256) void scan_passB(
    const float* __restrict__ endC,
    const float* __restrict__ nu_log, const float* __restrict__ theta_log,
    float* __restrict__ carryC)
{
    int tid = blockIdx.x * 256 + threadIdx.x;           // 0 .. 4095
    int p = tid & (PDIM - 1);
    int b = tid >> 10;
    float nu = expf(nu_log[p]);
    float th = expf(theta_log[p]);
    float e64 = expf(-nu * (float)CHUNK);
    float a = th * (float)CHUNK;
    float Lr = e64 * cosf(a), Li = e64 * sinf(a);
    float gr = 0.f, gi = 0.f;
    for (int c = 0; c < NCHUNK; ++c) {
        size_t idx = (((size_t)b * NCHUNK + c) * PDIM + p) * 2;
        float2 g; g.x = gr; g.y = gi;
        *(float2*)(carryC + idx) = g;
        float2 e = *(const float2*)(endC + idx);
        float nr = fmaf(Lr, gr, fmaf(-Li, gi, e.x));
        float ni = fmaf(Lr, gi, fmaf(Li, gr, e.y));
        gr = nr; gi = ni;
    }
}

// ---------------------------------------------------------------------------
// Scan pass C: re-scan each chunk from its entering state; x written in place
// over BuC (bf16 packed). State fp32.
// ---------------------------------------------------------------------------
__global__ __launch_bounds__(256) void scan_passC(
    uint32_t* __restrict__ BuC,
    const float* __restrict__ nu_log, const float* __restrict__ theta_log,
    const float* __restrict__ carryC)
{
    int tid = blockIdx.x * 256 + threadIdx.x;           // 0 .. 262143
    int p = tid & (PDIM - 1);
    int c = (tid >> 10) & (NCHUNK - 1);
    int b = tid >> 16;
    float nu = expf(nu_log[p]);
    float th = expf(theta_log[p]);
    float el = expf(-nu);
    float lr = el * cosf(th), li = el * sinf(th);
    float2 g = *(const float2*)(carryC + (size_t)tid * 2);
    float xr = g.x, xi = g.y;
    uint32_t* ptr = BuC + (size_t)(b * LSEQ + c * CHUNK) * PDIM + p;
    #pragma unroll 8
    for (int t = 0; t < CHUNK; ++t) {
        uint32_t v = ptr[(size_t)t * PDIM];
        float br = bfu2f(v & 0xffffu), bi = bfu2f(v >> 16);
        float nr = fmaf(lr, xr, fmaf(-li, xi, br));
        float ni = fmaf(lr, xi, fmaf(li, xr, bi));
        xr = nr; xi = ni;
        ptr[(size_t)t * PDIM] = (uint32_t)f2bf(xr) | ((uint32_t)f2bf(xi) << 16);
    }
}

// ---------------------------------------------------------------------------
extern "C" void kernel_launch(void* const* d_in, const int* in_sizes, int n_in,
                              void* d_out, int out_size, void* d_ws, size_t ws_size,
                              hipStream_t stream)
{
    (void)in_sizes; (void)n_in; (void)out_size; (void)ws_size;
    const float* U         = (const float*)d_in[0];
    const float* nu_log    = (const float*)d_in[1];
    const float* theta_log = (const float*)d_in[2];
    const float* B_re      = (const float*)d_in[3];
    const float* B_im      = (const float*)d_in[4];
    const float* C_re      = (const float*)d_in[5];
    const float* C_im      = (const float*)d_in[6];
    const float* Dv        = (const float*)d_in[7];
    const float* gamma_log = (const float*)d_in[8];
    float* out = (float*)d_out;

    // workspace layout (bytes): all power-of-2 sized, 256B aligned
    char* ws = (char*)d_ws;
    u16*      BuC    = (u16*)ws;                                   // 16384*2048*2 = 64 MB
    u16*      Ubf    = (u16*)(ws + (size_t)64 * 1024 * 1024);      // 32 MB
    u16*      Bcomb  = (u16*)(ws + (size_t)96 * 1024 * 1024);      // 4 MB
    u16*      Bcbf   = (u16*)(ws + (size_t)100 * 1024 * 1024);     // 4 MB
    float*    endC   = (float*)(ws + (size_t)104 * 1024 * 1024);   // 2 MB
    float*    carryC = (float*)(ws + (size_t)106 * 1024 * 1024);   // 2 MB
    // total 108 MB

    cvt_u_bf <<<(MDIM * HDIM) / (256 * 8), 256, 0, stream>>>(U, Ubf);
    prep_bcomb<<<(NBU * HDIM) / (256 * 8), 256, 0, stream>>>(B_re, B_im, gamma_log, Bcomb);
    prep_bc  <<<(HDIM * PDIM) / (256 * 4), 256, 0, stream>>>(C_re, C_im, Bcbf);

    dim3 g1(MDIM / 128, NBU / 128);   // 128 x 16
    gemm_bu_k<<<g1, 256, 0, stream>>>(Ubf, Bcomb, BuC);

    const int nscan = BSZ * NCHUNK * PDIM;               // 262144
    scan_passA<<<nscan / 256, 256, 0, stream>>>((const uint32_t*)BuC, nu_log, theta_log, endC);
    scan_passB<<<(BSZ * PDIM) / 256, 256, 0, stream>>>(endC, nu_log, theta_log, carryC);
    scan_passC<<<nscan / 256, 256, 0, stream>>>((uint32_t*)BuC, nu_log, theta_log, carryC);

    dim3 g3(MDIM / 128, HDIM / 128);  // 128 x 8
    gemm_out_k<<<g3, 256, 0, stream>>>(BuC, Bcbf, Dv, Ubf, out);
}

// Round 4
// 357.044 us; speedup vs baseline: 1.4849x; 1.0068x over previous
//
#include <hip/hip_runtime.h>
#include <cstdint>
#include <cstddef>

// Problem dims (fixed by the reference)
#define MDIM 16384    // B_SZ * L
#define HDIM 1024
#define PDIM 1024
#define LSEQ 4096
#define BSZ  4
#define CHUNK 64
#define NCHUNK 64     // LSEQ / CHUNK
#define NBU  2048     // 2*PDIM (interleaved re/im)

typedef float   floatx4  __attribute__((ext_vector_type(4)));
typedef __bf16  bf16x8   __attribute__((ext_vector_type(8)));
typedef unsigned short u16;
typedef unsigned short u16x8 __attribute__((ext_vector_type(8)));

// fp32 -> bf16 round-to-nearest-even
__device__ __forceinline__ u16 f2bf(float f) {
    union { float f; uint32_t u; } v; v.f = f;
    return (u16)((v.u + 0x7fffu + ((v.u >> 16) & 1u)) >> 16);
}
__device__ __forceinline__ float bfu2f(uint32_t bits16) {
    union { float f; uint32_t u; } v; v.u = bits16 << 16; return v.f;
}
__device__ __forceinline__ bf16x8 ldfrag(const u16* p) {
    return __builtin_bit_cast(bf16x8, *(const u16x8*)p);
}
// async global->LDS, 16B per lane; LDS deposit = uniform base + lane*16
__device__ __forceinline__ void gload16(const u16* g, u16* l) {
    __builtin_amdgcn_global_load_lds(
        (const __attribute__((address_space(1))) uint32_t*)g,
        (__attribute__((address_space(3))) uint32_t*)l, 16, 0, 0);
}

// ---------------------------------------------------------------------------
// bf16 MFMA GEMM core: C[128x128] tile, BK=64, global_load_lds staging,
// XOR-swizzled LDS (swizzle applied on the SOURCE address since the LDS
// deposit is fixed lane*16). A [M x KD], B [N x KD] row-major bf16.
// ---------------------------------------------------------------------------
template<int KD>
__device__ __forceinline__ void gemm_core(
    const u16* __restrict__ A, const u16* __restrict__ B,
    int m0, int n0, u16* sA, u16* sB, floatx4 acc[4][4])
{
    const int tid  = threadIdx.x;
    const int wave = tid >> 6, lane = tid & 63;
    const int lrow = lane & 15, lq = lane >> 4;
    const int wm = (wave >> 1) * 64, wn = (wave & 1) * 64;
    const int srow   = lane >> 3;            // 0..7 row within 8-row group
    const int schunk = (lane & 7) ^ srow;    // swizzled logical 16B chunk

    const u16* aptr = A + (size_t)(m0 + wave * 32 + srow) * KD + schunk * 8;
    const u16* bptr = B + (size_t)(n0 + wave * 32 + srow) * KD + schunk * 8;
    u16* sAw = sA + wave * 32 * 64;
    u16* sBw = sB + wave * 32 * 64;

    for (int k0 = 0; k0 < KD; k0 += 64) {
        #pragma unroll
        for (int i = 0; i < 4; ++i) {
            gload16(aptr + (size_t)i * 8 * KD + k0, sAw + i * 8 * 64);
            gload16(bptr + (size_t)i * 8 * KD + k0, sBw + i * 8 * 64);
        }
        __syncthreads();
        #pragma unroll
        for (int s = 0; s < 2; ++s) {
            bf16x8 af[4], bfr[4];
            #pragma unroll
            for (int mt = 0; mt < 4; ++mt) {
                int r = wm + mt * 16 + lrow;
                af[mt] = ldfrag(sA + r * 64 + (((s * 4 + lq) ^ (r & 7)) * 8));
            }
            #pragma unroll
            for (int nt = 0; nt < 4; ++nt) {
                int r = wn + nt * 16 + lrow;
                bfr[nt] = ldfrag(sB + r * 64 + (((s * 4 + lq) ^ (r & 7)) * 8));
            }
            #pragma unroll
            for (int mt = 0; mt < 4; ++mt)
                #pragma unroll
                for (int nt = 0; nt < 4; ++nt)
                    acc[mt][nt] = __builtin_amdgcn_mfma_f32_16x16x32_bf16(
                        af[mt], bfr[nt], acc[mt][nt], 0, 0, 0);
        }
        __syncthreads();
    }
}

// ---------------------------------------------------------------------------
// Kernel: Bu = Ubf @ Bcomb^T  (M=16384, N=2048, K=1024), output bf16.
// Epilogue: repack C tile through LDS -> coalesced 16B stores.
// Grid: x = n-tile (fastest, shares A), y = m-tile.
// ---------------------------------------------------------------------------
#define ST 136   // LDS repack row stride (u16): 272 B, 16B-aligned
__global__ __launch_bounds__(256) void gemm_bu_k(
    const u16* __restrict__ A, const u16* __restrict__ B, u16* __restrict__ O)
{
    __shared__ u16 smem[128 * ST];     // 34816 B; aliases sA|sB during K-loop
    u16* sA = smem;
    u16* sB = smem + 128 * 64;
    floatx4 acc[4][4] = {};
    const int n0 = blockIdx.x * 128, m0 = blockIdx.y * 128;
    gemm_core<HDIM>(A, B, m0, n0, sA, sB, acc);

    const int tid = threadIdx.x, wave = tid >> 6, lane = tid & 63;
    const int lrow = lane & 15, lq = lane >> 4;
    const int wm = (wave >> 1) * 64, wn = (wave & 1) * 64;

    // C tile -> LDS (row-major, stride ST)
    #pragma unroll
    for (int nt = 0; nt < 4; ++nt) {
        int col = wn + nt * 16 + lrow;
        #pragma unroll
        for (int mt = 0; mt < 4; ++mt)
            #pragma unroll
            for (int r = 0; r < 4; ++r) {
                int row = wm + mt * 16 + lq * 4 + r;
                smem[row * ST + col] = f2bf(acc[mt][nt][r]);
            }
    }
    __syncthreads();

    // coalesced store: thread t covers rows (t>>4)+16j, cols (t&15)*8..+7
    const int col = (tid & 15) * 8;
    const int rb  = tid >> 4;
    #pragma unroll
    for (int j = 0; j < 8; ++j) {
        int row = rb + j * 16;
        *(u16x8*)(O + (size_t)(m0 + row) * NBU + n0 + col) =
            *(const u16x8*)(smem + row * ST + col);
    }
}

// ---------------------------------------------------------------------------
// Kernel: out = Re(C x) + D.*u  (M=16384, N=1024, K=2048), output fp32.
// Grid: x = n-tile (fastest), y = m-tile.
// ---------------------------------------------------------------------------
__global__ __launch_bounds__(256) void gemm_out_k(
    const u16* __restrict__ A, const u16* __restrict__ B,
    const float* __restrict__ Dv, const u16* __restrict__ Ubf,
    float* __restrict__ O)
{
    __shared__ u16 sA[128 * 64];
    __shared__ u16 sB[128 * 64];
    floatx4 acc[4][4] = {};
    const int n0 = blockIdx.x * 128, m0 = blockIdx.y * 128;
    gemm_core<NBU>(A, B, m0, n0, sA, sB, acc);

    const int tid = threadIdx.x, wave = tid >> 6, lane = tid & 63;
    const int lrow = lane & 15, lq = lane >> 4;
    const int wm = (wave >> 1) * 64, wn = (wave & 1) * 64;
    #pragma unroll
    for (int nt = 0; nt < 4; ++nt) {
        int col = n0 + wn + nt * 16 + lrow;
        float d = Dv[col];
        #pragma unroll
        for (int mt = 0; mt < 4; ++mt)
            #pragma unroll
            for (int r = 0; r < 4; ++r) {
                int row = m0 + wm + mt * 16 + lq * 4 + r;
                size_t o = (size_t)row * HDIM + col;
                O[o] = acc[mt][nt][r] + d * bfu2f(Ubf[o]);
            }
    }
}

// ---------------------------------------------------------------------------
// Prep kernels: one-time fp32 -> bf16 conversions
// ---------------------------------------------------------------------------
__global__ __launch_bounds__(256) void cvt_u_bf(
    const float* __restrict__ in, u16* __restrict__ out)
{
    size_t i = ((size_t)blockIdx.x * 256 + threadIdx.x) * 8;
    float4 a = *(const float4*)(in + i);
    float4 b = *(const float4*)(in + i + 4);
    u16x8 w;
    w[0]=f2bf(a.x); w[1]=f2bf(a.y); w[2]=f2bf(a.z); w[3]=f2bf(a.w);
    w[4]=f2bf(b.x); w[5]=f2bf(b.y); w[6]=f2bf(b.z); w[7]=f2bf(b.w);
    *(u16x8*)(out + i) = w;
}

// Bcomb[n=2p+s][h] = bf16(gamma[p] * (s? B_im : B_re)[p][h])
__global__ __launch_bounds__(256) void prep_bcomb(
    const float* __restrict__ Bre, const float* __restrict__ Bim,
    const float* __restrict__ gamma_log, u16* __restrict__ out)
{
    int t = blockIdx.x * 256 + threadIdx.x;        // 2048*1024/8 = 262144
    int n = t >> 7;
    int h = (t & 127) * 8;
    int p = n >> 1, s = n & 1;
    const float* src = (s ? Bim : Bre) + (size_t)p * HDIM + h;
    float g = expf(gamma_log[p]);
    float4 a = *(const float4*)src;
    float4 b = *(const float4*)(src + 4);
    u16x8 w;
    w[0]=f2bf(a.x*g); w[1]=f2bf(a.y*g); w[2]=f2bf(a.z*g); w[3]=f2bf(a.w*g);
    w[4]=f2bf(b.x*g); w[5]=f2bf(b.y*g); w[6]=f2bf(b.z*g); w[7]=f2bf(b.w*g);
    *(u16x8*)(out + (size_t)n * HDIM + h) = w;
}

// Bcbf[h][2k]=bf16(Cre[h][k]); Bcbf[h][2k+1]=bf16(-Cim[h][k])
__global__ __launch_bounds__(256) void prep_bc(
    const float* __restrict__ Cre, const float* __restrict__ Cim,
    u16* __restrict__ out)
{
    int t = blockIdx.x * 256 + threadIdx.x;        // 1024*1024/4 = 262144
    int h = t >> 8;
    int k = (t & 255) * 4;
    float4 cr = *(const float4*)(Cre + (size_t)h * PDIM + k);
    float4 ci = *(const float4*)(Cim + (size_t)h * PDIM + k);
    u16x8 w;
    w[0]=f2bf(cr.x); w[1]=f2bf(-ci.x);
    w[2]=f2bf(cr.y); w[3]=f2bf(-ci.y);
    w[4]=f2bf(cr.z); w[5]=f2bf(-ci.z);
    w[6]=f2bf(cr.w); w[7]=f2bf(-ci.w);
    *(u16x8*)(out + (size_t)h * NBU + 2 * k) = w;
}

// ---------------------------------------------------------------------------
// Scan pass A: per-chunk local end states (bf16 Bu in, fp32 state out).
// 2 p's per thread (uint2 = 8B/lane).
// ---------------------------------------------------------------------------
__global__ __launch_bounds__(256) void scan_passA(
    const uint32_t* __restrict__ BuC,
    const float* __restrict__ nu_log, const float* __restrict__ theta_log,
    float* __restrict__ endC)
{
    int tid = blockIdx.x * 256 + threadIdx.x;           // 0 .. 131071
    int p0 = (tid & 511) * 2;
    int c  = (tid >> 9) & (NCHUNK - 1);
    int b  = tid >> 15;
    float nu0 = expf(nu_log[p0]),     th0 = expf(theta_log[p0]);
    float nu1 = expf(nu_log[p0 + 1]), th1 = expf(theta_log[p0 + 1]);
    float el0 = expf(-nu0), el1 = expf(-nu1);
    float lr0 = el0 * cosf(th0), li0 = el0 * sinf(th0);
    float lr1 = el1 * cosf(th1), li1 = el1 * sinf(th1);
    const uint32_t* src = BuC + (size_t)(b * LSEQ + c * CHUNK) * PDIM + p0;
    float xr0 = 0.f, xi0 = 0.f, xr1 = 0.f, xi1 = 0.f;
    #pragma unroll 8
    for (int t = 0; t < CHUNK; ++t) {
        uint2 v = *(const uint2*)(src + (size_t)t * PDIM);
        float br0 = bfu2f(v.x & 0xffffu), bi0 = bfu2f(v.x >> 16);
        float br1 = bfu2f(v.y & 0xffffu), bi1 = bfu2f(v.y >> 16);
        float nr0 = fmaf(lr0, xr0, fmaf(-li0, xi0, br0));
        float ni0 = fmaf(lr0, xi0, fmaf(li0, xr0, bi0));
        float nr1 = fmaf(lr1, xr1, fmaf(-li1, xi1, br1));
        float ni1 = fmaf(lr1, xi1, fmaf(li1, xr1, bi1));
        xr0 = nr0; xi0 = ni0; xr1 = nr1; xi1 = ni1;
    }
    float4 e; e.x = xr0; e.y = xi0; e.z = xr1; e.w = xi1;
    *(float4*)(endC + (((size_t)b * NCHUNK + c) * PDIM + p0) * 2) = e;
}

// ---------------------------------------------------------------------------
// Scan pass B: carry prefix across chunks. 2 p's per thread, loads batched
// in groups of 8 (independent) to avoid a 64-deep latency chain.
// ---------------------------------------------------------------------------
__global__ __launch_bounds__(256) void scan_passB(
    const float* __restrict__ endC,
    const float* __restrict__ nu_log, const float* __restrict__ theta_log,
    float* __restrict__ carryC)
{
    int tid = blockIdx.x * 256 + threadIdx.x;           // 0 .. 2047
    int p0 = (tid & 511) * 2;
    int b  = tid >> 9;
    float nu0 = expf(nu_log[p0]),     th0 = expf(theta_log[p0]);
    float nu1 = expf(nu_log[p0 + 1]), th1 = expf(theta_log[p0 + 1]);
    float e0 = expf(-nu0 * (float)CHUNK), a0 = th0 * (float)CHUNK;
    float e1 = expf(-nu1 * (float)CHUNK), a1 = th1 * (float)CHUNK;
    float Lr0 = e0 * cosf(a0), Li0 = e0 * sinf(a0);
    float Lr1 = e1 * cosf(a1), Li1 = e1 * sinf(a1);
    float gr0 = 0.f, gi0 = 0.f, gr1 = 0.f, gi1 = 0.f;
    for (int g = 0; g < 8; ++g) {
        float4 e[8];
        #pragma unroll
        for (int j = 0; j < 8; ++j)
            e[j] = *(const float4*)(endC + (((size_t)b * NCHUNK + g * 8 + j) * PDIM + p0) * 2);
        #pragma unroll
        for (int j = 0; j < 8; ++j) {
            size_t idx = (((size_t)b * NCHUNK + g * 8 + j) * PDIM + p0) * 2;
            float4 go; go.x = gr0; go.y = gi0; go.z = gr1; go.w = gi1;
            *(float4*)(carryC + idx) = go;
            float nr0 = fmaf(Lr0, gr0, fmaf(-Li0, gi0, e[j].x));
            float ni0 = fmaf(Lr0, gi0, fmaf(Li0, gr0, e[j].y));
            float nr1 = fmaf(Lr1, gr1, fmaf(-Li1, gi1, e[j].z));
            float ni1 = fmaf(Lr1, gi1, fmaf(Li1, gr1, e[j].w));
            gr0 = nr0; gi0 = ni0; gr1 = nr1; gi1 = ni1;
        }
    }
}

// ---------------------------------------------------------------------------
// Scan pass C: re-scan each chunk from its entering state; x written in place
// over BuC (bf16 packed). 2 p's per thread (uint2 = 8B/lane).
// ---------------------------------------------------------------------------
__global__ __launch_bounds__(256) void scan_passC(
    uint32_t* __restrict__ BuC,
    const float* __restrict__ nu_log, const float* __restrict__ theta_log,
    const float* __restrict__ carryC)
{
    int tid = blockIdx.x * 256 + threadIdx.x;           // 0 .. 131071
    int p0 = (tid & 511) * 2;
    int c  = (tid >> 9) & (NCHUNK - 1);
    int b  = tid >> 15;
    float nu0 = expf(nu_log[p0]),     th0 = expf(theta_log[p0]);
    float nu1 = expf(nu_log[p0 + 1]), th1 = expf(theta_log[p0 + 1]);
    float el0 = expf(-nu0), el1 = expf(-nu1);
    float lr0 = el0 * cosf(th0), li0 = el0 * sinf(th0);
    float lr1 = el1 * cosf(th1), li1 = el1 * sinf(th1);
    float4 g = *(const float4*)(carryC + (((size_t)b * NCHUNK + c) * PDIM + p0) * 2);
    float xr0 = g.x, xi0 = g.y, xr1 = g.z, xi1 = g.w;
    uint32_t* ptr = BuC + (size_t)(b * LSEQ + c * CHUNK) * PDIM + p0;
    #pragma unroll 8
    for (int t = 0; t < CHUNK; ++t) {
        uint32_t* q = ptr + (size_t)t * PDIM;
        uint2 v = *(const uint2*)q;
        float br0 = bfu2f(v.x & 0xffffu), bi0 = bfu2f(v.x >> 16);
        float br1 = bfu2f(v.y & 0xffffu), bi1 = bfu2f(v.y >> 16);
        float nr0 = fmaf(lr0, xr0, fmaf(-li0, xi0, br0));
        float ni0 = fmaf(lr0, xi0, fmaf(li0, xr0, bi0));
        float nr1 = fmaf(lr1, xr1, fmaf(-li1, xi1, br1));
        float ni1 = fmaf(lr1, xi1, fmaf(li1, xr1, bi1));
        xr0 = nr0; xi0 = ni0; xr1 = nr1; xi1 = ni1;
        uint2 o;
        o.x = (uint32_t)f2bf(xr0) | ((uint32_t)f2bf(xi0) << 16);
        o.y = (uint32_t)f2bf(xr1) | ((uint32_t)f2bf(xi1) << 16);
        *(uint2*)q = o;
    }
}

// ---------------------------------------------------------------------------
extern "C" void kernel_launch(void* const* d_in, const int* in_sizes, int n_in,
                              void* d_out, int out_size, void* d_ws, size_t ws_size,
                              hipStream_t stream)
{
    (void)in_sizes; (void)n_in; (void)out_size; (void)ws_size;
    const float* U         = (const float*)d_in[0];
    const float* nu_log    = (const float*)d_in[1];
    const float* theta_log = (const float*)d_in[2];
    const float* B_re      = (const float*)d_in[3];
    const float* B_im      = (const float*)d_in[4];
    const float* C_re      = (const float*)d_in[5];
    const float* C_im      = (const float*)d_in[6];
    const float* Dv        = (const float*)d_in[7];
    const float* gamma_log = (const float*)d_in[8];
    float* out = (float*)d_out;

    // workspace layout (bytes), 256B aligned
    char* ws = (char*)d_ws;
    u16*   BuC    = (u16*)ws;                                   // 64 MB
    u16*   Ubf    = (u16*)(ws + (size_t)64 * 1024 * 1024);      // 32 MB
    u16*   Bcomb  = (u16*)(ws + (size_t)96 * 1024 * 1024);      // 4 MB
    u16*   Bcbf   = (u16*)(ws + (size_t)100 * 1024 * 1024);     // 4 MB
    float* endC   = (float*)(ws + (size_t)104 * 1024 * 1024);   // 2 MB
    float* carryC = (float*)(ws + (size_t)106 * 1024 * 1024);   // 2 MB

    cvt_u_bf  <<<(MDIM * HDIM) / (256 * 8), 256, 0, stream>>>(U, Ubf);
    prep_bcomb<<<(NBU * HDIM) / (256 * 8), 256, 0, stream>>>(B_re, B_im, gamma_log, Bcomb);
    prep_bc   <<<(HDIM * PDIM) / (256 * 4), 256, 0, stream>>>(C_re, C_im, Bcbf);

    dim3 g1(NBU / 128, MDIM / 128);   // n fastest: 16 x 128
    gemm_bu_k<<<g1, 256, 0, stream>>>(Ubf, Bcomb, BuC);

    scan_passA<<<(BSZ * NCHUNK * PDIM / 2) / 256, 256, 0, stream>>>(
        (const uint32_t*)BuC, nu_log, theta_log, endC);
    scan_passB<<<(BSZ * PDIM / 2) / 256, 256, 0, stream>>>(endC, nu_log, theta_log, carryC);
    scan_passC<<<(BSZ * NCHUNK * PDIM / 2) / 256, 256, 0, stream>>>(
        (uint32_t*)BuC, nu_log, theta_log, carryC);

    dim3 g3(HDIM / 128, MDIM / 128);  // n fastest: 8 x 128
    gemm_out_k<<<g3, 256, 0, stream>>>(BuC, Bcbf, Dv, Ubf, out);
}

// Round 5
// 327.636 us; speedup vs baseline: 1.6182x; 1.0898x over previous
//
#include <hip/hip_runtime.h>
#include <cstdint>
#include <cstddef>

// Problem dims (fixed by the reference)
#define MDIM 16384    // B_SZ * L
#define HDIM 1024
#define PDIM 1024
#define LSEQ 4096
#define BSZ  4
#define CHUNK 64
#define NCHUNK 64     // LSEQ / CHUNK
#define NBU  2048     // 2*PDIM (interleaved re/im)

typedef float   floatx4  __attribute__((ext_vector_type(4)));
typedef __bf16  bf16x8   __attribute__((ext_vector_type(8)));
typedef unsigned short u16;
typedef unsigned short u16x8 __attribute__((ext_vector_type(8)));

// fp32 -> bf16 round-to-nearest-even
__device__ __forceinline__ u16 f2bf(float f) {
    union { float f; uint32_t u; } v; v.f = f;
    return (u16)((v.u + 0x7fffu + ((v.u >> 16) & 1u)) >> 16);
}
__device__ __forceinline__ float bfu2f(uint32_t bits16) {
    union { float f; uint32_t u; } v; v.u = bits16 << 16; return v.f;
}
__device__ __forceinline__ bf16x8 ldfrag(const u16* p) {
    return __builtin_bit_cast(bf16x8, *(const u16x8*)p);
}
// async global->LDS, 16B per lane; LDS deposit = uniform base + lane*16
__device__ __forceinline__ void gload16(const u16* g, u16* l) {
    __builtin_amdgcn_global_load_lds(
        (const __attribute__((address_space(1))) uint32_t*)g,
        (__attribute__((address_space(3))) uint32_t*)l, 16, 0, 0);
}

// ---------------------------------------------------------------------------
// bf16 MFMA GEMM core: C[128x128] tile, BK=64, global_load_lds staging,
// XOR-swizzled LDS (swizzle applied on the SOURCE address since the LDS
// deposit is fixed lane*16). A [M x KD], B [N x KD] row-major bf16.
// ---------------------------------------------------------------------------
template<int KD>
__device__ __forceinline__ void gemm_core(
    const u16* __restrict__ A, const u16* __restrict__ B,
    int m0, int n0, u16* sA, u16* sB, floatx4 acc[4][4])
{
    const int tid  = threadIdx.x;
    const int wave = tid >> 6, lane = tid & 63;
    const int lrow = lane & 15, lq = lane >> 4;
    const int wm = (wave >> 1) * 64, wn = (wave & 1) * 64;
    const int srow   = lane >> 3;            // 0..7 row within 8-row group
    const int schunk = (lane & 7) ^ srow;    // swizzled logical 16B chunk

    const u16* aptr = A + (size_t)(m0 + wave * 32 + srow) * KD + schunk * 8;
    const u16* bptr = B + (size_t)(n0 + wave * 32 + srow) * KD + schunk * 8;
    u16* sAw = sA + wave * 32 * 64;
    u16* sBw = sB + wave * 32 * 64;

    for (int k0 = 0; k0 < KD; k0 += 64) {
        #pragma unroll
        for (int i = 0; i < 4; ++i) {
            gload16(aptr + (size_t)i * 8 * KD + k0, sAw + i * 8 * 64);
            gload16(bptr + (size_t)i * 8 * KD + k0, sBw + i * 8 * 64);
        }
        __syncthreads();
        #pragma unroll
        for (int s = 0; s < 2; ++s) {
            bf16x8 af[4], bfr[4];
            #pragma unroll
            for (int mt = 0; mt < 4; ++mt) {
                int r = wm + mt * 16 + lrow;
                af[mt] = ldfrag(sA + r * 64 + (((s * 4 + lq) ^ (r & 7)) * 8));
            }
            #pragma unroll
            for (int nt = 0; nt < 4; ++nt) {
                int r = wn + nt * 16 + lrow;
                bfr[nt] = ldfrag(sB + r * 64 + (((s * 4 + lq) ^ (r & 7)) * 8));
            }
            #pragma unroll
            for (int mt = 0; mt < 4; ++mt)
                #pragma unroll
                for (int nt = 0; nt < 4; ++nt)
                    acc[mt][nt] = __builtin_amdgcn_mfma_f32_16x16x32_bf16(
                        af[mt], bfr[nt], acc[mt][nt], 0, 0, 0);
        }
        __syncthreads();
    }
}

// ---------------------------------------------------------------------------
// Kernel: Bu = Ubf @ Bcomb^T  (M=16384, N=2048, K=1024), output bf16.
// Epilogue: repack C tile through LDS -> coalesced 16B stores.
// Grid: 1-D, 2048 blocks. XCD-aware decode: x = d&7 (XCD via round-robin
// dispatch), each XCD owns a contiguous 16-m-tile band, sweeping all 16
// n-tiles per m-tile so the A m-tile stays resident in that XCD's L2.
// ---------------------------------------------------------------------------
#define ST 136   // LDS repack row stride (u16): 272 B, 16B-aligned
__global__ __launch_bounds__(256) void gemm_bu_k(
    const u16* __restrict__ A, const u16* __restrict__ B, u16* __restrict__ O)
{
    __shared__ u16 smem[128 * ST];     // 34816 B; aliases sA|sB during K-loop
    u16* sA = smem;
    u16* sB = smem + 128 * 64;
    floatx4 acc[4][4] = {};
    const int d = blockIdx.x;
    const int xcd = d & 7, s = d >> 3;               // s: 0..255
    const int m0 = (xcd * 16 + (s >> 4)) * 128;      // m-tile band per XCD
    const int n0 = (s & 15) * 128;
    gemm_core<HDIM>(A, B, m0, n0, sA, sB, acc);

    const int tid = threadIdx.x, wave = tid >> 6, lane = tid & 63;
    const int lrow = lane & 15, lq = lane >> 4;
    const int wm = (wave >> 1) * 64, wn = (wave & 1) * 64;

    // C tile -> LDS (row-major, stride ST)
    #pragma unroll
    for (int nt = 0; nt < 4; ++nt) {
        int col = wn + nt * 16 + lrow;
        #pragma unroll
        for (int mt = 0; mt < 4; ++mt)
            #pragma unroll
            for (int r = 0; r < 4; ++r) {
                int row = wm + mt * 16 + lq * 4 + r;
                smem[row * ST + col] = f2bf(acc[mt][nt][r]);
            }
    }
    __syncthreads();

    // coalesced store: thread t covers rows (t>>4)+16j, cols (t&15)*8..+7
    const int col = (tid & 15) * 8;
    const int rb  = tid >> 4;
    #pragma unroll
    for (int j = 0; j < 8; ++j) {
        int row = rb + j * 16;
        *(u16x8*)(O + (size_t)(m0 + row) * NBU + n0 + col) =
            *(const u16x8*)(smem + row * ST + col);
    }
}

// ---------------------------------------------------------------------------
// Kernel: out = Re(C x) + D.*u  (M=16384, N=1024, K=2048), output fp32.
// Grid: 1-D, 1024 blocks, XCD-aware decode (16-m-tile band per XCD,
// 8 n-tiles swept per m-tile).
// ---------------------------------------------------------------------------
__global__ __launch_bounds__(256) void gemm_out_k(
    const u16* __restrict__ A, const u16* __restrict__ B,
    const float* __restrict__ Dv, const u16* __restrict__ Ubf,
    float* __restrict__ O)
{
    __shared__ u16 sA[128 * 64];
    __shared__ u16 sB[128 * 64];
    floatx4 acc[4][4] = {};
    const int d = blockIdx.x;
    const int xcd = d & 7, s = d >> 3;               // s: 0..127
    const int m0 = (xcd * 16 + (s >> 3)) * 128;      // m-tile band per XCD
    const int n0 = (s & 7) * 128;
    gemm_core<NBU>(A, B, m0, n0, sA, sB, acc);

    const int tid = threadIdx.x, wave = tid >> 6, lane = tid & 63;
    const int lrow = lane & 15, lq = lane >> 4;
    const int wm = (wave >> 1) * 64, wn = (wave & 1) * 64;
    #pragma unroll
    for (int nt = 0; nt < 4; ++nt) {
        int col = n0 + wn + nt * 16 + lrow;
        float dval = Dv[col];
        #pragma unroll
        for (int mt = 0; mt < 4; ++mt)
            #pragma unroll
            for (int r = 0; r < 4; ++r) {
                int row = m0 + wm + mt * 16 + lq * 4 + r;
                size_t o = (size_t)row * HDIM + col;
                O[o] = acc[mt][nt][r] + dval * bfu2f(Ubf[o]);
            }
    }
}

// ---------------------------------------------------------------------------
// Merged prep kernel (single launch): band 0 = U->bf16 (8192 blocks),
// band 1 = Bcomb (1024 blocks), band 2 = Bcbf (1024 blocks).
// ---------------------------------------------------------------------------
__global__ __launch_bounds__(256) void prep_all(
    const float* __restrict__ U, u16* __restrict__ Ubf,
    const float* __restrict__ Bre, const float* __restrict__ Bim,
    const float* __restrict__ gamma_log, u16* __restrict__ Bcomb,
    const float* __restrict__ Cre, const float* __restrict__ Cim,
    u16* __restrict__ Bcbf)
{
    const int bid = blockIdx.x;
    if (bid < 8192) {
        // U fp32 -> bf16, 8 elems/thread
        size_t i = ((size_t)bid * 256 + threadIdx.x) * 8;
        float4 a = *(const float4*)(U + i);
        float4 b = *(const float4*)(U + i + 4);
        u16x8 w;
        w[0]=f2bf(a.x); w[1]=f2bf(a.y); w[2]=f2bf(a.z); w[3]=f2bf(a.w);
        w[4]=f2bf(b.x); w[5]=f2bf(b.y); w[6]=f2bf(b.z); w[7]=f2bf(b.w);
        *(u16x8*)(Ubf + i) = w;
    } else if (bid < 9216) {
        // Bcomb[n=2p+s][h] = bf16(gamma[p] * (s? B_im : B_re)[p][h])
        int t = (bid - 8192) * 256 + threadIdx.x;      // 0 .. 262143
        int n = t >> 7;
        int h = (t & 127) * 8;
        int p = n >> 1, sflag = n & 1;
        const float* src = (sflag ? Bim : Bre) + (size_t)p * HDIM + h;
        float g = expf(gamma_log[p]);
        float4 a = *(const float4*)src;
        float4 b = *(const float4*)(src + 4);
        u16x8 w;
        w[0]=f2bf(a.x*g); w[1]=f2bf(a.y*g); w[2]=f2bf(a.z*g); w[3]=f2bf(a.w*g);
        w[4]=f2bf(b.x*g); w[5]=f2bf(b.y*g); w[6]=f2bf(b.z*g); w[7]=f2bf(b.w*g);
        *(u16x8*)(Bcomb + (size_t)n * HDIM + h) = w;
    } else {
        // Bcbf[h][2k]=bf16(Cre[h][k]); Bcbf[h][2k+1]=bf16(-Cim[h][k])
        int t = (bid - 9216) * 256 + threadIdx.x;      // 0 .. 262143
        int h = t >> 8;
        int k = (t & 255) * 4;
        float4 cr = *(const float4*)(Cre + (size_t)h * PDIM + k);
        float4 ci = *(const float4*)(Cim + (size_t)h * PDIM + k);
        u16x8 w;
        w[0]=f2bf(cr.x); w[1]=f2bf(-ci.x);
        w[2]=f2bf(cr.y); w[3]=f2bf(-ci.y);
        w[4]=f2bf(cr.z); w[5]=f2bf(-ci.z);
        w[6]=f2bf(cr.w); w[7]=f2bf(-ci.w);
        *(u16x8*)(Bcbf + (size_t)h * NBU + 2 * k) = w;
    }
}

// ---------------------------------------------------------------------------
// Scan pass A: per-chunk local end states (bf16 Bu in, fp32 state out).
// 2 p's per thread (uint2 = 8B/lane).
// ---------------------------------------------------------------------------
__global__ __launch_bounds__(256) void scan_passA(
    const uint32_t* __restrict__ BuC,
    const float* __restrict__ nu_log, const float* __restrict__ theta_log,
    float* __restrict__ endC)
{
    int tid = blockIdx.x * 256 + threadIdx.x;           // 0 .. 131071
    int p0 = (tid & 511) * 2;
    int c  = (tid >> 9) & (NCHUNK - 1);
    int b  = tid >> 15;
    float nu0 = expf(nu_log[p0]),     th0 = expf(theta_log[p0]);
    float nu1 = expf(nu_log[p0 + 1]), th1 = expf(theta_log[p0 + 1]);
    float el0 = expf(-nu0), el1 = expf(-nu1);
    float lr0 = el0 * cosf(th0), li0 = el0 * sinf(th0);
    float lr1 = el1 * cosf(th1), li1 = el1 * sinf(th1);
    const uint32_t* src = BuC + (size_t)(b * LSEQ + c * CHUNK) * PDIM + p0;
    float xr0 = 0.f, xi0 = 0.f, xr1 = 0.f, xi1 = 0.f;
    #pragma unroll 8
    for (int t = 0; t < CHUNK; ++t) {
        uint2 v = *(const uint2*)(src + (size_t)t * PDIM);
        float br0 = bfu2f(v.x & 0xffffu), bi0 = bfu2f(v.x >> 16);
        float br1 = bfu2f(v.y & 0xffffu), bi1 = bfu2f(v.y >> 16);
        float nr0 = fmaf(lr0, xr0, fmaf(-li0, xi0, br0));
        float ni0 = fmaf(lr0, xi0, fmaf(li0, xr0, bi0));
        float nr1 = fmaf(lr1, xr1, fmaf(-li1, xi1, br1));
        float ni1 = fmaf(lr1, xi1, fmaf(li1, xr1, bi1));
        xr0 = nr0; xi0 = ni0; xr1 = nr1; xi1 = ni1;
    }
    float4 e; e.x = xr0; e.y = xi0; e.z = xr1; e.w = xi1;
    *(float4*)(endC + (((size_t)b * NCHUNK + c) * PDIM + p0) * 2) = e;
}

// ---------------------------------------------------------------------------
// Scan pass B: carry prefix across chunks. 2 p's per thread, loads batched
// in groups of 8 (independent) to avoid a 64-deep latency chain.
// ---------------------------------------------------------------------------
__global__ __launch_bounds__(256) void scan_passB(
    const float* __restrict__ endC,
    const float* __restrict__ nu_log, const float* __restrict__ theta_log,
    float* __restrict__ carryC)
{
    int tid = blockIdx.x * 256 + threadIdx.x;           // 0 .. 2047
    int p0 = (tid & 511) * 2;
    int b  = tid >> 9;
    float nu0 = expf(nu_log[p0]),     th0 = expf(theta_log[p0]);
    float nu1 = expf(nu_log[p0 + 1]), th1 = expf(theta_log[p0 + 1]);
    float e0 = expf(-nu0 * (float)CHUNK), a0 = th0 * (float)CHUNK;
    float e1 = expf(-nu1 * (float)CHUNK), a1 = th1 * (float)CHUNK;
    float Lr0 = e0 * cosf(a0), Li0 = e0 * sinf(a0);
    float Lr1 = e1 * cosf(a1), Li1 = e1 * sinf(a1);
    float gr0 = 0.f, gi0 = 0.f, gr1 = 0.f, gi1 = 0.f;
    for (int g = 0; g < 8; ++g) {
        float4 e[8];
        #pragma unroll
        for (int j = 0; j < 8; ++j)
            e[j] = *(const float4*)(endC + (((size_t)b * NCHUNK + g * 8 + j) * PDIM + p0) * 2);
        #pragma unroll
        for (int j = 0; j < 8; ++j) {
            size_t idx = (((size_t)b * NCHUNK + g * 8 + j) * PDIM + p0) * 2;
            float4 go; go.x = gr0; go.y = gi0; go.z = gr1; go.w = gi1;
            *(float4*)(carryC + idx) = go;
            float nr0 = fmaf(Lr0, gr0, fmaf(-Li0, gi0, e[j].x));
            float ni0 = fmaf(Lr0, gi0, fmaf(Li0, gr0, e[j].y));
            float nr1 = fmaf(Lr1, gr1, fmaf(-Li1, gi1, e[j].z));
            float ni1 = fmaf(Lr1, gi1, fmaf(Li1, gr1, e[j].w));
            gr0 = nr0; gi0 = ni0; gr1 = nr1; gi1 = ni1;
        }
    }
}

// ---------------------------------------------------------------------------
// Scan pass C: re-scan each chunk from its entering state; x written in place
// over BuC (bf16 packed). 2 p's per thread (uint2 = 8B/lane).
// ---------------------------------------------------------------------------
__global__ __launch_bounds__(256) void scan_passC(
    uint32_t* __restrict__ BuC,
    const float* __restrict__ nu_log, const float* __restrict__ theta_log,
    const float* __restrict__ carryC)
{
    int tid = blockIdx.x * 256 + threadIdx.x;           // 0 .. 131071
    int p0 = (tid & 511) * 2;
    int c  = (tid >> 9) & (NCHUNK - 1);
    int b  = tid >> 15;
    float nu0 = expf(nu_log[p0]),     th0 = expf(theta_log[p0]);
    float nu1 = expf(nu_log[p0 + 1]), th1 = expf(theta_log[p0 + 1]);
    float el0 = expf(-nu0), el1 = expf(-nu1);
    float lr0 = el0 * cosf(th0), li0 = el0 * sinf(th0);
    float lr1 = el1 * cosf(th1), li1 = el1 * sinf(th1);
    float4 g = *(const float4*)(carryC + (((size_t)b * NCHUNK + c) * PDIM + p0) * 2);
    float xr0 = g.x, xi0 = g.y, xr1 = g.z, xi1 = g.w;
    uint32_t* ptr = BuC + (size_t)(b * LSEQ + c * CHUNK) * PDIM + p0;
    #pragma unroll 8
    for (int t = 0; t < CHUNK; ++t) {
        uint32_t* q = ptr + (size_t)t * PDIM;
        uint2 v = *(const uint2*)q;
        float br0 = bfu2f(v.x & 0xffffu), bi0 = bfu2f(v.x >> 16);
        float br1 = bfu2f(v.y & 0xffffu), bi1 = bfu2f(v.y >> 16);
        float nr0 = fmaf(lr0, xr0, fmaf(-li0, xi0, br0));
        float ni0 = fmaf(lr0, xi0, fmaf(li0, xr0, bi0));
        float nr1 = fmaf(lr1, xr1, fmaf(-li1, xi1, br1));
        float ni1 = fmaf(lr1, xi1, fmaf(li1, xr1, bi1));
        xr0 = nr0; xi0 = ni0; xr1 = nr1; xi1 = ni1;
        uint2 o;
        o.x = (uint32_t)f2bf(xr0) | ((uint32_t)f2bf(xi0) << 16);
        o.y = (uint32_t)f2bf(xr1) | ((uint32_t)f2bf(xi1) << 16);
        *(uint2*)q = o;
    }
}

// ---------------------------------------------------------------------------
extern "C" void kernel_launch(void* const* d_in, const int* in_sizes, int n_in,
                              void* d_out, int out_size, void* d_ws, size_t ws_size,
                              hipStream_t stream)
{
    (void)in_sizes; (void)n_in; (void)out_size; (void)ws_size;
    const float* U         = (const float*)d_in[0];
    const float* nu_log    = (const float*)d_in[1];
    const float* theta_log = (const float*)d_in[2];
    const float* B_re      = (const float*)d_in[3];
    const float* B_im      = (const float*)d_in[4];
    const float* C_re      = (const float*)d_in[5];
    const float* C_im      = (const float*)d_in[6];
    const float* Dv        = (const float*)d_in[7];
    const float* gamma_log = (const float*)d_in[8];
    float* out = (float*)d_out;

    // workspace layout (bytes), 256B aligned
    char* ws = (char*)d_ws;
    u16*   BuC    = (u16*)ws;                                   // 64 MB
    u16*   Ubf    = (u16*)(ws + (size_t)64 * 1024 * 1024);      // 32 MB
    u16*   Bcomb  = (u16*)(ws + (size_t)96 * 1024 * 1024);      // 4 MB
    u16*   Bcbf   = (u16*)(ws + (size_t)100 * 1024 * 1024);     // 4 MB
    float* endC   = (float*)(ws + (size_t)104 * 1024 * 1024);   // 2 MB
    float* carryC = (float*)(ws + (size_t)106 * 1024 * 1024);   // 2 MB

    prep_all<<<8192 + 1024 + 1024, 256, 0, stream>>>(
        U, Ubf, B_re, B_im, gamma_log, Bcomb, C_re, C_im, Bcbf);

    gemm_bu_k<<<2048, 256, 0, stream>>>(Ubf, Bcomb, BuC);

    scan_passA<<<(BSZ * NCHUNK * PDIM / 2) / 256, 256, 0, stream>>>(
        (const uint32_t*)BuC, nu_log, theta_log, endC);
    scan_passB<<<(BSZ * PDIM / 2) / 256, 256, 0, stream>>>(endC, nu_log, theta_log, carryC);
    scan_passC<<<(BSZ * NCHUNK * PDIM / 2) / 256, 256, 0, stream>>>(
        (uint32_t*)BuC, nu_log, theta_log, carryC);

    gemm_out_k<<<1024, 256, 0, stream>>>(BuC, Bcbf, Dv, Ubf, out);
}